// Round 1
// baseline (110.186 us; speedup 1.0000x reference)
//
#include <hip/hip_runtime.h>

constexpr int NJ = 31;

struct M34 {
    float r[9];  // row-major 3x3 rotation
    float t[3];  // translation
};

// Build RT_j = R4(q) @ T_j  as a 3x4 affine (bottom row is [0,0,0,1]).
// T_j = offsets[j] with translation column scaled by bone length.
__device__ __forceinline__ void make_RT(int j, float4 q, float len,
                                        const float* __restrict__ soff,
                                        float Rr[9], float Rt[3]) {
    const float w = q.x, x = q.y, y = q.z, z = q.w;
    const float two_s = 2.0f / (w * w + x * x + y * y + z * z);
    float R[9];
    R[0] = 1.0f - two_s * (y * y + z * z);
    R[1] = two_s * (x * y - z * w);
    R[2] = two_s * (x * z + y * w);
    R[3] = two_s * (x * y + z * w);
    R[4] = 1.0f - two_s * (x * x + z * z);
    R[5] = two_s * (y * z - x * w);
    R[6] = two_s * (x * z + x * w);  // placeholder, fixed below
    R[6] = two_s * (x * z - y * w);
    R[7] = two_s * (y * z + x * w);
    R[8] = 1.0f - two_s * (x * x + y * y);

    const float* O = soff + j * 16;  // row-major 4x4
    const float ot0 = O[3] * len, ot1 = O[7] * len, ot2 = O[11] * len;
#pragma unroll
    for (int r = 0; r < 3; ++r) {
#pragma unroll
        for (int c = 0; c < 3; ++c) {
            Rr[r * 3 + c] = R[r * 3 + 0] * O[0 * 4 + c] +
                            R[r * 3 + 1] * O[1 * 4 + c] +
                            R[r * 3 + 2] * O[2 * 4 + c];
        }
        Rt[r] = R[r * 3 + 0] * ot0 + R[r * 3 + 1] * ot1 + R[r * 3 + 2] * ot2;
    }
}

// child = parent ∘ RT_j ; writes the output position for joint j.
__device__ __forceinline__ M34 step(const M34& P, int j,
                                    const float4* __restrict__ jq,
                                    const float* __restrict__ fb,
                                    const float* __restrict__ soff,
                                    float4* __restrict__ outv) {
    float Rr[9], Rt[3];
    make_RT(j, jq[j], fb[j], soff, Rr, Rt);
    M34 C;
#pragma unroll
    for (int r = 0; r < 3; ++r) {
#pragma unroll
        for (int c = 0; c < 3; ++c) {
            C.r[r * 3 + c] = P.r[r * 3 + 0] * Rr[0 * 3 + c] +
                             P.r[r * 3 + 1] * Rr[1 * 3 + c] +
                             P.r[r * 3 + 2] * Rr[2 * 3 + c];
        }
        C.t[r] = P.r[r * 3 + 0] * Rt[0] + P.r[r * 3 + 1] * Rt[1] +
                 P.r[r * 3 + 2] * Rt[2] + P.t[r];
    }
    outv[j] = make_float4(C.t[0], C.t[1], C.t[2], 1.0f);
    return C;
}

__global__ __launch_bounds__(256) void fk_layer_kernel(
    const float* __restrict__ root_position,  // (B,3)
    const float* __restrict__ joint,          // (B, NJ*4)
    const float* __restrict__ fbl,            // (B, NJ)
    const float* __restrict__ offsets,        // (NJ,4,4)
    float* __restrict__ out,                  // (B, NJ, 4)
    int B) {
    __shared__ float soff[NJ * 16];
    for (int i = threadIdx.x; i < NJ * 16; i += blockDim.x) soff[i] = offsets[i];
    __syncthreads();

    const int b = blockIdx.x * blockDim.x + threadIdx.x;
    if (b >= B) return;

    const float4* jq = reinterpret_cast<const float4*>(joint + (size_t)b * (NJ * 4));
    const float* fb = fbl + (size_t)b * NJ;
    float4* outv = reinterpret_cast<float4*>(out + (size_t)b * (NJ * 4));

    const float rx = root_position[(size_t)b * 3 + 0] * 100.0f;
    const float ry = root_position[(size_t)b * 3 + 1] * 100.0f;
    const float rz = root_position[(size_t)b * 3 + 2] * 100.0f;

    // Joint 0: root_T (identity rotation, translation = 100*root) ∘ RT_0
    M34 M0;
    {
        float Rr[9], Rt[3];
        make_RT(0, jq[0], fb[0], soff, Rr, Rt);
#pragma unroll
        for (int i = 0; i < 9; ++i) M0.r[i] = Rr[i];
        M0.t[0] = Rt[0] + rx;
        M0.t[1] = Rt[1] + ry;
        M0.t[2] = Rt[2] + rz;
        outv[0] = make_float4(M0.t[0], M0.t[1], M0.t[2], 1.0f);
    }

    // Chains: 0→1..5, 0→6..10, 0→11..15 (save 13), 13→16..20, 13→21..25, 13→26..30
    M34 cur = M0;
#pragma unroll
    for (int j = 1; j <= 5; ++j) cur = step(cur, j, jq, fb, soff, outv);

    cur = M0;
#pragma unroll
    for (int j = 6; j <= 10; ++j) cur = step(cur, j, jq, fb, soff, outv);

    cur = M0;
    M34 M13;
#pragma unroll
    for (int j = 11; j <= 15; ++j) {
        cur = step(cur, j, jq, fb, soff, outv);
        if (j == 13) M13 = cur;
    }

    cur = M13;
#pragma unroll
    for (int j = 16; j <= 20; ++j) cur = step(cur, j, jq, fb, soff, outv);

    cur = M13;
#pragma unroll
    for (int j = 21; j <= 25; ++j) cur = step(cur, j, jq, fb, soff, outv);

    cur = M13;
#pragma unroll
    for (int j = 26; j <= 30; ++j) cur = step(cur, j, jq, fb, soff, outv);
}

extern "C" void kernel_launch(void* const* d_in, const int* in_sizes, int n_in,
                              void* d_out, int out_size, void* d_ws, size_t ws_size,
                              hipStream_t stream) {
    const float* root = (const float*)d_in[0];
    const float* joint = (const float*)d_in[1];
    const float* fbl = (const float*)d_in[2];
    const float* offs = (const float*)d_in[3];
    float* out = (float*)d_out;

    const int B = in_sizes[0] / 3;  // root_position is (B,3)
    const int block = 256;
    const int grid = (B + block - 1) / block;
    fk_layer_kernel<<<grid, block, 0, stream>>>(root, joint, fbl, offs, out, B);
}

// Round 2
// 44.099 us; speedup vs baseline: 2.4986x; 2.4986x over previous
//
#include <hip/hip_runtime.h>

constexpr int NJ = 31;        // joints
constexpr int RPB = 128;      // batch rows per block
constexpr int JF = NJ * 4;    // 124 floats per row (joint row / output row)

struct M34 {
    float r[9];  // row-major 3x3
    float t[3];
};

// RT_j = R4(q) @ T_j as 3x4 affine; T_j = offsets[j] with translation scaled by len.
__device__ __forceinline__ void make_RT(int j, float4 q, float len,
                                        const float* __restrict__ soff,
                                        float Rr[9], float Rt[3]) {
    const float w = q.x, x = q.y, y = q.z, z = q.w;
    const float two_s = 2.0f / (w * w + x * x + y * y + z * z);
    float R[9];
    R[0] = 1.0f - two_s * (y * y + z * z);
    R[1] = two_s * (x * y - z * w);
    R[2] = two_s * (x * z + y * w);
    R[3] = two_s * (x * y + z * w);
    R[4] = 1.0f - two_s * (x * x + z * z);
    R[5] = two_s * (y * z - x * w);
    R[6] = two_s * (x * z - y * w);
    R[7] = two_s * (y * z + x * w);
    R[8] = 1.0f - two_s * (x * x + y * y);

    const float* O = soff + j * 16;  // row-major 4x4, LDS broadcast reads
    const float ot0 = O[3] * len, ot1 = O[7] * len, ot2 = O[11] * len;
#pragma unroll
    for (int r = 0; r < 3; ++r) {
#pragma unroll
        for (int c = 0; c < 3; ++c) {
            Rr[r * 3 + c] = R[r * 3 + 0] * O[0 * 4 + c] +
                            R[r * 3 + 1] * O[1 * 4 + c] +
                            R[r * 3 + 2] * O[2 * 4 + c];
        }
        Rt[r] = R[r * 3 + 0] * ot0 + R[r * 3 + 1] * ot1 + R[r * 3 + 2] * ot2;
    }
}

// child = parent ∘ RT_j; writes output position (t,1) back into sj (overwrites quat j).
__device__ __forceinline__ M34 step(const M34& P, int j,
                                    float* __restrict__ srow,   // this thread's row in sj
                                    const float* __restrict__ sfrow,
                                    const float* __restrict__ soff) {
    float4 q = *reinterpret_cast<const float4*>(&srow[j * 4]);
    float Rr[9], Rt[3];
    make_RT(j, q, sfrow[j], soff, Rr, Rt);
    M34 C;
#pragma unroll
    for (int r = 0; r < 3; ++r) {
#pragma unroll
        for (int c = 0; c < 3; ++c) {
            C.r[r * 3 + c] = P.r[r * 3 + 0] * Rr[0 * 3 + c] +
                             P.r[r * 3 + 1] * Rr[1 * 3 + c] +
                             P.r[r * 3 + 2] * Rr[2 * 3 + c];
        }
        C.t[r] = P.r[r * 3 + 0] * Rt[0] + P.r[r * 3 + 1] * Rt[1] +
                 P.r[r * 3 + 2] * Rt[2] + P.t[r];
    }
    *reinterpret_cast<float4*>(&srow[j * 4]) = make_float4(C.t[0], C.t[1], C.t[2], 1.0f);
    return C;
}

__global__ __launch_bounds__(128) void fk_layer_kernel(
    const float* __restrict__ root_position,  // (B,3)
    const float* __restrict__ joint,          // (B, NJ*4)
    const float* __restrict__ fbl,            // (B, NJ)
    const float* __restrict__ offsets,        // (NJ,4,4)
    float* __restrict__ out,                  // (B, NJ, 4)
    int B) {
    __shared__ float sj[RPB * JF];    // 63488 B: quats in, outputs overwrite in place
    __shared__ float sfb[RPB * NJ];   // 15872 B
    __shared__ float soff[NJ * 16];   // 1984 B

    const int tid = threadIdx.x;
    const int w = tid >> 6;
    const int lane = tid & 63;
    const long long rowBase = (long long)blockIdx.x * RPB;

    // offsets -> LDS (tiny)
    for (int i = tid; i < NJ * 16; i += RPB) soff[i] = offsets[i];

    // joint tile -> LDS: 62 chunks x 1KB, async direct-to-LDS, width=16
    {
        const float* gbase = joint + rowBase * JF;
#pragma unroll
        for (int i = 0; i < 31; ++i) {
            const int chunk = w * 31 + i;                     // 0..61
            const float* g = gbase + chunk * 256 + lane * 4;  // per-lane 16B
            float* l = sj + chunk * 256;                      // wave-uniform base
            __builtin_amdgcn_global_load_lds(
                (const __attribute__((address_space(1))) unsigned int*)g,
                (__attribute__((address_space(3))) unsigned int*)l, 16, 0, 0);
        }
    }
    // fbl tile -> LDS: 62 chunks x 256B, width=4
    {
        const float* gbase = fbl + rowBase * NJ;
#pragma unroll
        for (int i = 0; i < 31; ++i) {
            const int chunk = w * 31 + i;                 // 0..61
            const float* g = gbase + chunk * 64 + lane;   // per-lane 4B
            float* l = sfb + chunk * 64;                  // wave-uniform base
            __builtin_amdgcn_global_load_lds(
                (const __attribute__((address_space(1))) unsigned int*)g,
                (__attribute__((address_space(3))) unsigned int*)l, 4, 0, 0);
        }
    }
    __syncthreads();  // drains vmcnt before LDS use

    // ---- compute: thread tid owns batch row (rowBase + tid) ----
    float* srow = sj + tid * JF;
    const float* sfrow = sfb + tid * NJ;
    const long long b = rowBase + tid;

    const float rx = root_position[b * 3 + 0] * 100.0f;
    const float ry = root_position[b * 3 + 1] * 100.0f;
    const float rz = root_position[b * 3 + 2] * 100.0f;

    M34 M0;
    {
        float4 q = *reinterpret_cast<const float4*>(&srow[0]);
        float Rr[9], Rt[3];
        make_RT(0, q, sfrow[0], soff, Rr, Rt);
#pragma unroll
        for (int i = 0; i < 9; ++i) M0.r[i] = Rr[i];
        M0.t[0] = Rt[0] + rx;
        M0.t[1] = Rt[1] + ry;
        M0.t[2] = Rt[2] + rz;
        *reinterpret_cast<float4*>(&srow[0]) =
            make_float4(M0.t[0], M0.t[1], M0.t[2], 1.0f);
    }

    // chains: 0→1..5, 0→6..10, 0→11..15 (save 13), 13→16..20, 13→21..25, 13→26..30
    M34 cur = M0;
#pragma unroll
    for (int j = 1; j <= 5; ++j) cur = step(cur, j, srow, sfrow, soff);

    cur = M0;
#pragma unroll
    for (int j = 6; j <= 10; ++j) cur = step(cur, j, srow, sfrow, soff);

    cur = M0;
    M34 M13;
#pragma unroll
    for (int j = 11; j <= 15; ++j) {
        cur = step(cur, j, srow, sfrow, soff);
        if (j == 13) M13 = cur;
    }

    cur = M13;
#pragma unroll
    for (int j = 16; j <= 20; ++j) cur = step(cur, j, srow, sfrow, soff);

    cur = M13;
#pragma unroll
    for (int j = 21; j <= 25; ++j) cur = step(cur, j, srow, sfrow, soff);

    cur = M13;
#pragma unroll
    for (int j = 26; j <= 30; ++j) cur = step(cur, j, srow, sfrow, soff);

    __syncthreads();

    // ---- coalesced store of the whole tile (RPB*JF floats) ----
    float4* gout = reinterpret_cast<float4*>(out + rowBase * JF);
#pragma unroll
    for (int i = 0; i < 31; ++i) {
        const int idx = i * RPB + tid;  // float4 index, 0..3967
        gout[idx] = *reinterpret_cast<const float4*>(&sj[idx * 4]);
    }
}

extern "C" void kernel_launch(void* const* d_in, const int* in_sizes, int n_in,
                              void* d_out, int out_size, void* d_ws, size_t ws_size,
                              hipStream_t stream) {
    const float* root = (const float*)d_in[0];
    const float* joint = (const float*)d_in[1];
    const float* fblp = (const float*)d_in[2];
    const float* offs = (const float*)d_in[3];
    float* out = (float*)d_out;

    const int B = in_sizes[0] / 3;  // root_position is (B,3); B = 131072 (multiple of RPB)
    const int grid = B / RPB;
    fk_layer_kernel<<<grid, RPB, 0, stream>>>(root, joint, fblp, offs, out, B);
}